// Round 10
// baseline (163.231 us; speedup 1.0000x reference)
//
#include <hip/hip_runtime.h>
#include <hip/hip_fp16.h>
#include <cstdint>

// ---------------------------------------------------------------------------
// SingleDeformConv on MI355X (gfx950)
// data (8,64,128,128) f32; w (64,64,3,3); b (64); w_off (18,64,3,3); b_off(18);
// w_mod (9,64,3,3); b_mod (9).  out = relu(deform_conv(...)) (8,64,128,128) f32
//
// R20 -> R21: R15-exact structure (best measured 160.7: 2-row conv27,
// R12-exact deform, R15 prep) + XCD image-affinity swizzle on conv27 and
// deform. Mechanism: per-image working set xt(2MB)+offP(1.77MB) = 3.8MB fits
// one XCD's 4MB L2. Default round-robin (XCD=bid%8) spreads all 8 images
// across every XCD (16MB+ per-XCD working set -> gathers served from L3 at
// ~2x L2 latency). Remap blk=(bid%8)*chunk+bid/8 gives each XCD exactly one
// image: conv27 halo reads, offP writes, deform corner gathers + params all
// L2-resident. Bijective (2048%8=1024%8=0), bit-identical math, zero
// structural risk. If neutral -> next round declares the practical ceiling
// (deform 45.3 floor across 8 variants; ~46us harness poison; total ~160).
// ---------------------------------------------------------------------------

typedef _Float16 half8 __attribute__((ext_vector_type(8)));
typedef __attribute__((ext_vector_type(4))) float floatx4;

// pack two floats -> f16x2 dword (RNE)
__device__ __forceinline__ unsigned int pack2h(float lo, float hi) {
    __half2 h = __floats2half2_rn(lo, hi);
    union { __half2 h; unsigned int u; } cv; cv.h = h;
    return cv.u;
}
// blend one f16x2 dword from 4 corners with broadcast __half2 weights
__device__ __forceinline__ unsigned int blend2h(unsigned int a, unsigned int b,
                                                unsigned int c, unsigned int d,
                                                const __half2* w) {
    union { unsigned int u; __half2 h; } A, B, C, D, O;
    A.u = a; B.u = b; C.u = c; D.u = d;
    __half2 s = __hmul2(A.h, w[0]);
    s = __hfma2(B.h, w[1], s);
    s = __hfma2(C.h, w[2], s);
    s = __hfma2(D.h, w[3], s);
    O.h = s;
    return O.u;
}

// Workspace layout (bytes) — R15 layout
#define OFF_DATAT 0u               // [8][16384][64] f16   = 16777216 B
#define OFF_OFFP  16777216u        // [8][9][3][16384] f32 = 14155776 B (dy,dx,mask)
#define OFF_WM    30932992u        // [64][576] f16        = 73728 B
#define OFF_W27   31006720u        // wq[9][2][2][4][16][8] f16 = 36864 B
#define OFF_B27   31043584u        // [32] f32             = 128 B
// total 31043712 B

// ---------------------------------------------------------------------------
// Kernel 1: prep = NCHW f32 -> NHWC f16 transpose (blocks 0..2047)
//           + weight packing / bias27 (blocks 2048..2263)   [R15-exact]
// ---------------------------------------------------------------------------
__global__ __launch_bounds__(256) void prep_k(const float* __restrict__ x,
                                              unsigned short* __restrict__ xt,
                                              const float* __restrict__ w,
                                              const float* __restrict__ w_off,
                                              const float* __restrict__ w_mod,
                                              const float* __restrict__ b_off,
                                              const float* __restrict__ b_mod,
                                              unsigned short* __restrict__ wpackM,
                                              unsigned short* __restrict__ wq,
                                              float* __restrict__ bias27) {
    __shared__ float tile[64][65];
    int blk = blockIdx.x;
    if (blk < 2048) {                              // ---- transpose ----
        int b    = blk >> 8;
        int pos0 = (blk & 255) << 6;
        int lane = threadIdx.x & 63;
        int g    = threadIdx.x >> 6;
        for (int c = g; c < 64; c += 4)
            tile[c][lane] = x[(((b << 6) + c) << 14) + pos0 + lane];
        __syncthreads();
        int c2 = lane & 31;
        for (int i = g; i < 32; i += 4) {
            int pr = (i << 1) + (lane >> 5);
            unsigned int d = pack2h(tile[c2 << 1][pr], tile[(c2 << 1) + 1][pr]);
            *(unsigned int*)&xt[((size_t)((b << 14) + pos0 + pr) << 6) + (c2 << 1)] = d;
        }
        return;
    }
    // ---- weight packing ----
    int t = (blk - 2048) * 256 + threadIdx.x;
    if (t < 64 * 576) {
        int o = t / 576, kk = t % 576;
        int k = kk >> 6, c = kk & 63;
        wpackM[t] = __half_as_ushort(__float2half_rn(w[(o * 64 + c) * 9 + k]));
        return;
    }
    t -= 64 * 576;
    if (t < 32 * 576) {
        int o = t / 576, kk = t % 576;
        int k = kk >> 6, c = kk & 63;
        float v = 0.f;
        if (o < 18)      v = w_off[(o * 64 + c) * 9 + k];
        else if (o < 27) v = w_mod[((o - 18) * 64 + c) * 9 + k];
        int s = o >> 4, r = o & 15;
        int chh = c >> 5, q = (c >> 3) & 3, j = c & 7;
        int dst = (((((k << 1) + chh) << 1) + s) << 9) + (q << 7) + (r << 3) + j;
        wq[dst] = __half_as_ushort(__float2half_rn(v));
        if (kk == 0) bias27[o] = (o < 18) ? b_off[o] : (o < 27 ? b_mod[o - 18] : 0.f);
    }
}

// ---------------------------------------------------------------------------
// Kernel 2: offset/mask conv (27 ch, padded to 32) — LDS-free implicit GEMM.
// R15-exact 2-row patches + XCD image-affinity swizzle (grid 1024 = 8 x 128;
// XCD x gets logical blocks [x*128, x*128+128) = exactly image b = x).
// ---------------------------------------------------------------------------
__global__ __launch_bounds__(256) void conv27_k(const unsigned short* __restrict__ xt,
                                                const unsigned short* __restrict__ wq,
                                                const float* __restrict__ bias27,
                                                float* __restrict__ offP) {
    int blk   = ((blockIdx.x & 7) << 7) + (blockIdx.x >> 3);  // XCD swizzle
    int b     = blk >> 7;
    int patch = blk & 127;
    int m     = patch >> 1;                         // row pair
    int h     = patch & 1;                          // col half
    int tid   = threadIdx.x;
    int lane  = tid & 63, wv = tid >> 6;
    int r = lane & 15, q = lane >> 4;

    const unsigned short* xb = xt + ((size_t)b << 20);
    int rb  = (m << 1) - 1;                         // top source row of patch
    int cxb = (h << 6) + (wv << 4) + r - 1;         // per-lane source col base
    int chq = (q << 3);                             // lane channel sub-chunk

    floatx4 acc[4] = {};                            // [s*2 + tr]
    #pragma unroll
    for (int k = 0; k < 9; ++k) {
        int ki = k / 3, kj = k % 3;
        #pragma unroll
        for (int chh = 0; chh < 2; ++chh) {
            int abase = ((((k << 1) + chh) << 1) << 9) + (lane << 3);
            half8 a0 = *(const half8*)&wq[abase];           // s=0 block
            half8 a1 = *(const half8*)&wq[abase + 512];     // s=1 block
            #pragma unroll
            for (int tr = 0; tr < 2; ++tr) {
                int sy = rb + tr + ki;
                int sx = cxb + kj;
                half8 bf = {};
                if ((unsigned)sy < 128u && (unsigned)sx < 128u)
                    bf = *(const half8*)&xb[(size_t)(((sy << 7) + sx) << 6) + (chh << 5) + chq];
                acc[0 + tr] = __builtin_amdgcn_mfma_f32_16x16x32_f16(a0, bf, acc[0 + tr], 0, 0, 0);
                acc[2 + tr] = __builtin_amdgcn_mfma_f32_16x16x32_f16(a1, bf, acc[2 + tr], 0, 0, 0);
            }
        }
    }

    #pragma unroll
    for (int s = 0; s < 2; ++s) {
        #pragma unroll
        for (int tr = 0; tr < 2; ++tr) {
            #pragma unroll
            for (int reg = 0; reg < 4; ++reg) {
                int oc = (s << 4) + (q << 2) + reg;
                if (oc >= 27) continue;
                int pos = (((m << 1) + tr) << 7) + (h << 6) + (wv << 4) + r;
                float v = acc[(s << 1) + tr][reg] + bias27[oc];
                int kk, comp;
                if (oc < 18) { kk = oc >> 1; comp = oc & 1; }
                else         { kk = oc - 18; comp = 2; v = 2.f / (1.f + __expf(-v)); }
                offP[(size_t)(((b * 9 + kk) * 3 + comp) << 14) + pos] = v;
            }
        }
    }
}

// ---------------------------------------------------------------------------
// Kernel 3: main deformable conv — R12/R15-exact two-tap pipelined datapath
// + XCD image-affinity swizzle (grid 2048 = 8 x 256; XCD x gets exactly
// image b = x: xt 2MB + offP 1.77MB L2-resident per XCD).
// ---------------------------------------------------------------------------
__global__ __launch_bounds__(256, 3) void deform_main_k(const unsigned short* __restrict__ xt,
                                                        const unsigned short* __restrict__ wpackM,
                                                        const float* __restrict__ offP,
                                                        const float* __restrict__ bias,
                                                        float* __restrict__ out) {
    __shared__ ushort4 pOff[576];                   // 4608 B  corner pos-indices
    __shared__ uint4   pW[576];                     // 9216 B  4x f16x2 weights
    __shared__ unsigned short samp[2][64][72];      // 18432 B B-tile (double buf)
    int blk  = ((blockIdx.x & 7) << 8) + (blockIdx.x >> 3);  // XCD swizzle
    int b    = blk >> 8;
    int pos0 = (blk & 255) << 6;
    int tid  = threadIdx.x;
    int lane = tid & 63, wv = tid >> 6;
    int r = lane & 15, q = lane >> 4;
    int pg = lane >> 3;                             // position subgroup 0..7
    int j8 = lane & 7;                              // channel chunk (8 f16 = 16B)

    const char* xbb = (const char*)(xt + ((size_t)b << 20));

    // ---- phase 0: params, one thread per (tap,pos) entry ----
    for (int e = tid; e < 576; e += 256) {
        int k = e >> 6, p = e & 63;
        int pos = pos0 + p;
        const float* offk = offP + ((size_t)((b * 9 + k) * 3) << 14);
        float dy = offk[pos];
        float dx = offk[16384 + pos];
        float m  = offk[32768 + pos];
        float py = (float)(pos >> 7) + (float)(k / 3 - 1) + dy;
        float px = (float)(pos & 127) + (float)(k % 3 - 1) + dx;
        float y0f = floorf(py), x0f = floorf(px);
        int y0 = (int)y0f, x0 = (int)x0f;
        float wy1 = py - y0f, wx1 = px - x0f;
        float wy0 = 1.f - wy1, wx0 = 1.f - wx1;
        bool vy0 = (y0 >= 0) && (y0 < 128);
        bool vy1 = (y0 >= -1) && (y0 < 127);
        bool vx0 = (x0 >= 0) && (x0 < 128);
        bool vx1 = (x0 >= -1) && (x0 < 127);
        float w00 = (vy0 && vx0) ? m * wy0 * wx0 : 0.f;
        float w01 = (vy0 && vx1) ? m * wy0 * wx1 : 0.f;
        float w10 = (vy1 && vx0) ? m * wy1 * wx0 : 0.f;
        float w11 = (vy1 && vx1) ? m * wy1 * wx1 : 0.f;
        int y0c = min(max(y0, 0), 127), y1c = min(max(y0 + 1, 0), 127);
        int x0c = min(max(x0, 0), 127), x1c = min(max(x0 + 1, 0), 127);
        ushort4 io;
        io.x = (unsigned short)((y0c << 7) + x0c);
        io.y = (unsigned short)((y0c << 7) + x1c);
        io.z = (unsigned short)((y1c << 7) + x0c);
        io.w = (unsigned short)((y1c << 7) + x1c);
        pOff[e] = io;
        union { uint4 u; __half2 h[4]; } pw;
        pw.h[0] = __float2half2_rn(w00);
        pw.h[1] = __float2half2_rn(w01);
        pw.h[2] = __float2half2_rn(w10);
        pw.h[3] = __float2half2_rn(w11);
        pW[e] = pw.u;
    }
    __syncthreads();                                // pOff/pW ready

    floatx4 acc[4] = {};
    const char* xp = xbb + (j8 << 4);               // per-lane channel-chunk base
    const unsigned short* wrow = wpackM + ((wv << 4) + r) * 576 + (q << 3);

    uint4   c00[2][2], c01[2][2], c10[2][2], c11[2][2];  // [set][i]
    uint4   cwS[2][2];                              // weights per set
    ushort4 nio[2];                                 // staged params (next issue)
    uint4   ncw[2];
    half8   afC[2], afN[2];                         // A-frags, current / next

    auto readParams = [&](int k) {
        #pragma unroll
        for (int i = 0; i < 2; ++i) {
            int e  = (k << 6) + (wv << 4) + (i << 3) + pg;
            nio[i] = pOff[e];
            ncw[i] = pW[e];
        }
    };
    auto issueInto = [&](int s) {                   // s is compile-time at all call sites
        #pragma unroll
        for (int i = 0; i < 2; ++i) {
            cwS[s][i] = ncw[i];
            c00[s][i] = *(const uint4*)(xp + ((int)nio[i].x << 7));
            c01[s][i] = *(const uint4*)(xp + ((int)nio[i].y << 7));
            c10[s][i] = *(const uint4*)(xp + ((int)nio[i].z << 7));
            c11[s][i] = *(const uint4*)(xp + ((int)nio[i].w << 7));
        }
    };
    auto blendStore = [&](int s, int buf) {         // s, buf compile-time
        #pragma unroll
        for (int i = 0; i < 2; ++i) {
            int p = (wv << 4) + (i << 3) + pg;
            union { uint4 u; __half2 h[4]; } W; W.u = cwS[s][i];
            uint4 o4;
            o4.x = blend2h(c00[s][i].x, c01[s][i].x, c10[s][i].x, c11[s][i].x, W.h);
            o4.y = blend2h(c00[s][i].y, c01[s][i].y, c10[s][i].y, c11[s][i].y, W.h);
            o4.z = blend2h(c00[s][i].z, c01[s][i].z, c10[s][i].z, c11[s][i].z, W.h);
            o4.w = blend2h(c00[s][i].w, c01[s][i].w, c10[s][i].w, c11[s][i].w, W.h);
            *(uint4*)&samp[buf][p][j8 << 3] = o4;
        }
    };

    // LDS-only barrier: commit this wave's ds_writes (lgkmcnt), then barrier.
    auto ldsBarrier = [&]() {
        asm volatile("s_waitcnt lgkmcnt(0)\n\ts_barrier" ::: "memory");
    };

    // prologue: taps 0 and 1 into the pipe; params(2) staged
    readParams(0); issueInto(0);
    readParams(1); issueInto(1);
    afC[0] = *(const half8*)&wrow[0];
    afC[1] = *(const half8*)&wrow[32];
    blendStore(0, 0);                               // blend tap0 -> samp[0]
    readParams(2);

    #pragma unroll
    for (int k = 0; k < 9; ++k) {
        if (k <= 6) issueInto(k & 1);               // corners for tap k+2
        if (k < 8) {
            afN[0] = *(const half8*)&wrow[((k + 1) << 6)];
            afN[1] = *(const half8*)&wrow[((k + 1) << 6) + 32];
        }
        ldsBarrier();                               // samp[k&1] complete block-wide
        #pragma unroll
        for (int ch = 0; ch < 2; ++ch) {
            #pragma unroll
            for (int nt = 0; nt < 4; ++nt) {
                half8 bfrag = *(const half8*)&samp[k & 1][(nt << 4) + r][(ch << 5) + (q << 3)];
                acc[nt] = __builtin_amdgcn_mfma_f32_16x16x32_f16(afC[ch], bfrag, acc[nt], 0, 0, 0);
            }
        }
        if (k < 8) {
            blendStore((k + 1) & 1, (k + 1) & 1);   // corners issued at body k-1
            if (k <= 5) readParams(k + 3);          // params for issue at body k+1
            afC[0] = afN[0];
            afC[1] = afN[1];
        }
    }

    #pragma unroll
    for (int nt = 0; nt < 4; ++nt) {
        #pragma unroll
        for (int reg = 0; reg < 4; ++reg) {
            int oc  = (wv << 4) + (q << 2) + reg;
            int pos = pos0 + (nt << 4) + r;
            float v = acc[nt][reg] + bias[oc];
            out[(size_t)(((b << 6) + oc) << 14) + pos] = fmaxf(v, 0.f);
        }
    }
}

// ---------------------------------------------------------------------------
extern "C" void kernel_launch(void* const* d_in, const int* in_sizes, int n_in,
                              void* d_out, int out_size, void* d_ws, size_t ws_size,
                              hipStream_t stream) {
    const float* data  = (const float*)d_in[0];
    const float* w     = (const float*)d_in[1];
    const float* bias  = (const float*)d_in[2];
    const float* w_off = (const float*)d_in[3];
    const float* b_off = (const float*)d_in[4];
    const float* w_mod = (const float*)d_in[5];
    const float* b_mod = (const float*)d_in[6];
    float* out = (float*)d_out;

    char* ws = (char*)d_ws;
    unsigned short* dataT   = (unsigned short*)(ws + OFF_DATAT);
    float*          offP    = (float*)(ws + OFF_OFFP);
    unsigned short* wpackM  = (unsigned short*)(ws + OFF_WM);
    unsigned short* wq      = (unsigned short*)(ws + OFF_W27);
    float*          bias27  = (float*)(ws + OFF_B27);

    prep_k<<<2264, 256, 0, stream>>>(data, dataT, w, w_off, w_mod,
                                     b_off, b_mod, wpackM, wq, bias27);
    conv27_k<<<1024, 256, 0, stream>>>(dataT, wq, bias27, offP);
    deform_main_k<<<2048, 256, 0, stream>>>(dataT, wpackM, offP, bias, out);
}

// Round 11
// 161.125 us; speedup vs baseline: 1.0131x; 1.0131x over previous
//
#include <hip/hip_runtime.h>
#include <hip/hip_fp16.h>
#include <cstdint>

// ---------------------------------------------------------------------------
// SingleDeformConv on MI355X (gfx950)
// data (8,64,128,128) f32; w (64,64,3,3); b (64); w_off (18,64,3,3); b_off(18);
// w_mod (9,64,3,3); b_mod (9).  out = relu(deform_conv(...)) (8,64,128,128) f32
//
// R21 -> R22 (CONSOLIDATION): best-of-session per-kernel configuration.
//  - prep, conv27: R15-exact (the 160.7us-best total; conv27 swizzle dropped,
//    unproven and possibly -3us in R21).
//  - deform: R12-exact datapath + XCD image-affinity swizzle -- the only
//    deform variant that beat baseline on its own counters (44.7us vs 45.3,
//    FETCH 40.9 -> 15.5MB: gathers L2-served).
// Ceiling arithmetic (per R21 pre-commitment): deform floor ~44.7
// (serialization-bound: MFMA 8%, VALU 22%, LDS ~15%, TA ~20%, L2-resident --
// 9 structural variants all >= it); conv27+gap ~28 (2 levers null); prep
// ~10-12; harness poison fill ~46 (256MiB @ 5.85TB/s, fixed). Sum ~160 =
// observed. Run noise +/-2-3us.
// ---------------------------------------------------------------------------

typedef _Float16 half8 __attribute__((ext_vector_type(8)));
typedef __attribute__((ext_vector_type(4))) float floatx4;

// pack two floats -> f16x2 dword (RNE)
__device__ __forceinline__ unsigned int pack2h(float lo, float hi) {
    __half2 h = __floats2half2_rn(lo, hi);
    union { __half2 h; unsigned int u; } cv; cv.h = h;
    return cv.u;
}
// blend one f16x2 dword from 4 corners with broadcast __half2 weights
__device__ __forceinline__ unsigned int blend2h(unsigned int a, unsigned int b,
                                                unsigned int c, unsigned int d,
                                                const __half2* w) {
    union { unsigned int u; __half2 h; } A, B, C, D, O;
    A.u = a; B.u = b; C.u = c; D.u = d;
    __half2 s = __hmul2(A.h, w[0]);
    s = __hfma2(B.h, w[1], s);
    s = __hfma2(C.h, w[2], s);
    s = __hfma2(D.h, w[3], s);
    O.h = s;
    return O.u;
}

// Workspace layout (bytes) — R15 layout
#define OFF_DATAT 0u               // [8][16384][64] f16   = 16777216 B
#define OFF_OFFP  16777216u        // [8][9][3][16384] f32 = 14155776 B (dy,dx,mask)
#define OFF_WM    30932992u        // [64][576] f16        = 73728 B
#define OFF_W27   31006720u        // wq[9][2][2][4][16][8] f16 = 36864 B
#define OFF_B27   31043584u        // [32] f32             = 128 B
// total 31043712 B

// ---------------------------------------------------------------------------
// Kernel 1: prep = NCHW f32 -> NHWC f16 transpose (blocks 0..2047)
//           + weight packing / bias27 (blocks 2048..2263)   [R15-exact]
// ---------------------------------------------------------------------------
__global__ __launch_bounds__(256) void prep_k(const float* __restrict__ x,
                                              unsigned short* __restrict__ xt,
                                              const float* __restrict__ w,
                                              const float* __restrict__ w_off,
                                              const float* __restrict__ w_mod,
                                              const float* __restrict__ b_off,
                                              const float* __restrict__ b_mod,
                                              unsigned short* __restrict__ wpackM,
                                              unsigned short* __restrict__ wq,
                                              float* __restrict__ bias27) {
    __shared__ float tile[64][65];
    int blk = blockIdx.x;
    if (blk < 2048) {                              // ---- transpose ----
        int b    = blk >> 8;
        int pos0 = (blk & 255) << 6;
        int lane = threadIdx.x & 63;
        int g    = threadIdx.x >> 6;
        for (int c = g; c < 64; c += 4)
            tile[c][lane] = x[(((b << 6) + c) << 14) + pos0 + lane];
        __syncthreads();
        int c2 = lane & 31;
        for (int i = g; i < 32; i += 4) {
            int pr = (i << 1) + (lane >> 5);
            unsigned int d = pack2h(tile[c2 << 1][pr], tile[(c2 << 1) + 1][pr]);
            *(unsigned int*)&xt[((size_t)((b << 14) + pos0 + pr) << 6) + (c2 << 1)] = d;
        }
        return;
    }
    // ---- weight packing ----
    int t = (blk - 2048) * 256 + threadIdx.x;
    if (t < 64 * 576) {
        int o = t / 576, kk = t % 576;
        int k = kk >> 6, c = kk & 63;
        wpackM[t] = __half_as_ushort(__float2half_rn(w[(o * 64 + c) * 9 + k]));
        return;
    }
    t -= 64 * 576;
    if (t < 32 * 576) {
        int o = t / 576, kk = t % 576;
        int k = kk >> 6, c = kk & 63;
        float v = 0.f;
        if (o < 18)      v = w_off[(o * 64 + c) * 9 + k];
        else if (o < 27) v = w_mod[((o - 18) * 64 + c) * 9 + k];
        int s = o >> 4, r = o & 15;
        int chh = c >> 5, q = (c >> 3) & 3, j = c & 7;
        int dst = (((((k << 1) + chh) << 1) + s) << 9) + (q << 7) + (r << 3) + j;
        wq[dst] = __half_as_ushort(__float2half_rn(v));
        if (kk == 0) bias27[o] = (o < 18) ? b_off[o] : (o < 27 ? b_mod[o - 18] : 0.f);
    }
}

// ---------------------------------------------------------------------------
// Kernel 2: offset/mask conv (27 ch, padded to 32) — LDS-free implicit GEMM.
// R15-exact: 2-row patches, grid 1024, no swizzle.
// ---------------------------------------------------------------------------
__global__ __launch_bounds__(256) void conv27_k(const unsigned short* __restrict__ xt,
                                                const unsigned short* __restrict__ wq,
                                                const float* __restrict__ bias27,
                                                float* __restrict__ offP) {
    int blk   = blockIdx.x;                         // 1024 = 8 b * 128 patches
    int b     = blk >> 7;
    int patch = blk & 127;
    int m     = patch >> 1;                         // row pair
    int h     = patch & 1;                          // col half
    int tid   = threadIdx.x;
    int lane  = tid & 63, wv = tid >> 6;
    int r = lane & 15, q = lane >> 4;

    const unsigned short* xb = xt + ((size_t)b << 20);
    int rb  = (m << 1) - 1;                         // top source row of patch
    int cxb = (h << 6) + (wv << 4) + r - 1;         // per-lane source col base
    int chq = (q << 3);                             // lane channel sub-chunk

    floatx4 acc[4] = {};                            // [s*2 + tr]
    #pragma unroll
    for (int k = 0; k < 9; ++k) {
        int ki = k / 3, kj = k % 3;
        #pragma unroll
        for (int chh = 0; chh < 2; ++chh) {
            int abase = ((((k << 1) + chh) << 1) << 9) + (lane << 3);
            half8 a0 = *(const half8*)&wq[abase];           // s=0 block
            half8 a1 = *(const half8*)&wq[abase + 512];     // s=1 block
            #pragma unroll
            for (int tr = 0; tr < 2; ++tr) {
                int sy = rb + tr + ki;
                int sx = cxb + kj;
                half8 bf = {};
                if ((unsigned)sy < 128u && (unsigned)sx < 128u)
                    bf = *(const half8*)&xb[(size_t)(((sy << 7) + sx) << 6) + (chh << 5) + chq];
                acc[0 + tr] = __builtin_amdgcn_mfma_f32_16x16x32_f16(a0, bf, acc[0 + tr], 0, 0, 0);
                acc[2 + tr] = __builtin_amdgcn_mfma_f32_16x16x32_f16(a1, bf, acc[2 + tr], 0, 0, 0);
            }
        }
    }

    #pragma unroll
    for (int s = 0; s < 2; ++s) {
        #pragma unroll
        for (int tr = 0; tr < 2; ++tr) {
            #pragma unroll
            for (int reg = 0; reg < 4; ++reg) {
                int oc = (s << 4) + (q << 2) + reg;
                if (oc >= 27) continue;
                int pos = (((m << 1) + tr) << 7) + (h << 6) + (wv << 4) + r;
                float v = acc[(s << 1) + tr][reg] + bias27[oc];
                int kk, comp;
                if (oc < 18) { kk = oc >> 1; comp = oc & 1; }
                else         { kk = oc - 18; comp = 2; v = 2.f / (1.f + __expf(-v)); }
                offP[(size_t)(((b * 9 + kk) * 3 + comp) << 14) + pos] = v;
            }
        }
    }
}

// ---------------------------------------------------------------------------
// Kernel 3: main deformable conv — R12-exact two-tap pipelined datapath
// + XCD image-affinity swizzle (proven: dur 45.3 -> 44.7, FETCH 40.9 -> 15.5MB;
// XCD x gets exactly image b = x: xt 2MB + offP 1.77MB L2-resident).
// ---------------------------------------------------------------------------
__global__ __launch_bounds__(256, 3) void deform_main_k(const unsigned short* __restrict__ xt,
                                                        const unsigned short* __restrict__ wpackM,
                                                        const float* __restrict__ offP,
                                                        const float* __restrict__ bias,
                                                        float* __restrict__ out) {
    __shared__ ushort4 pOff[576];                   // 4608 B  corner pos-indices
    __shared__ uint4   pW[576];                     // 9216 B  4x f16x2 weights
    __shared__ unsigned short samp[2][64][72];      // 18432 B B-tile (double buf)
    int blk  = ((blockIdx.x & 7) << 8) + (blockIdx.x >> 3);  // XCD swizzle
    int b    = blk >> 8;
    int pos0 = (blk & 255) << 6;
    int tid  = threadIdx.x;
    int lane = tid & 63, wv = tid >> 6;
    int r = lane & 15, q = lane >> 4;
    int pg = lane >> 3;                             // position subgroup 0..7
    int j8 = lane & 7;                              // channel chunk (8 f16 = 16B)

    const char* xbb = (const char*)(xt + ((size_t)b << 20));

    // ---- phase 0: params, one thread per (tap,pos) entry ----
    for (int e = tid; e < 576; e += 256) {
        int k = e >> 6, p = e & 63;
        int pos = pos0 + p;
        const float* offk = offP + ((size_t)((b * 9 + k) * 3) << 14);
        float dy = offk[pos];
        float dx = offk[16384 + pos];
        float m  = offk[32768 + pos];
        float py = (float)(pos >> 7) + (float)(k / 3 - 1) + dy;
        float px = (float)(pos & 127) + (float)(k % 3 - 1) + dx;
        float y0f = floorf(py), x0f = floorf(px);
        int y0 = (int)y0f, x0 = (int)x0f;
        float wy1 = py - y0f, wx1 = px - x0f;
        float wy0 = 1.f - wy1, wx0 = 1.f - wx1;
        bool vy0 = (y0 >= 0) && (y0 < 128);
        bool vy1 = (y0 >= -1) && (y0 < 127);
        bool vx0 = (x0 >= 0) && (x0 < 128);
        bool vx1 = (x0 >= -1) && (x0 < 127);
        float w00 = (vy0 && vx0) ? m * wy0 * wx0 : 0.f;
        float w01 = (vy0 && vx1) ? m * wy0 * wx1 : 0.f;
        float w10 = (vy1 && vx0) ? m * wy1 * wx0 : 0.f;
        float w11 = (vy1 && vx1) ? m * wy1 * wx1 : 0.f;
        int y0c = min(max(y0, 0), 127), y1c = min(max(y0 + 1, 0), 127);
        int x0c = min(max(x0, 0), 127), x1c = min(max(x0 + 1, 0), 127);
        ushort4 io;
        io.x = (unsigned short)((y0c << 7) + x0c);
        io.y = (unsigned short)((y0c << 7) + x1c);
        io.z = (unsigned short)((y1c << 7) + x0c);
        io.w = (unsigned short)((y1c << 7) + x1c);
        pOff[e] = io;
        union { uint4 u; __half2 h[4]; } pw;
        pw.h[0] = __float2half2_rn(w00);
        pw.h[1] = __float2half2_rn(w01);
        pw.h[2] = __float2half2_rn(w10);
        pw.h[3] = __float2half2_rn(w11);
        pW[e] = pw.u;
    }
    __syncthreads();                                // pOff/pW ready

    floatx4 acc[4] = {};
    const char* xp = xbb + (j8 << 4);               // per-lane channel-chunk base
    const unsigned short* wrow = wpackM + ((wv << 4) + r) * 576 + (q << 3);

    uint4   c00[2][2], c01[2][2], c10[2][2], c11[2][2];  // [set][i]
    uint4   cwS[2][2];                              // weights per set
    ushort4 nio[2];                                 // staged params (next issue)
    uint4   ncw[2];
    half8   afC[2], afN[2];                         // A-frags, current / next

    auto readParams = [&](int k) {
        #pragma unroll
        for (int i = 0; i < 2; ++i) {
            int e  = (k << 6) + (wv << 4) + (i << 3) + pg;
            nio[i] = pOff[e];
            ncw[i] = pW[e];
        }
    };
    auto issueInto = [&](int s) {                   // s is compile-time at all call sites
        #pragma unroll
        for (int i = 0; i < 2; ++i) {
            cwS[s][i] = ncw[i];
            c00[s][i] = *(const uint4*)(xp + ((int)nio[i].x << 7));
            c01[s][i] = *(const uint4*)(xp + ((int)nio[i].y << 7));
            c10[s][i] = *(const uint4*)(xp + ((int)nio[i].z << 7));
            c11[s][i] = *(const uint4*)(xp + ((int)nio[i].w << 7));
        }
    };
    auto blendStore = [&](int s, int buf) {         // s, buf compile-time
        #pragma unroll
        for (int i = 0; i < 2; ++i) {
            int p = (wv << 4) + (i << 3) + pg;
            union { uint4 u; __half2 h[4]; } W; W.u = cwS[s][i];
            uint4 o4;
            o4.x = blend2h(c00[s][i].x, c01[s][i].x, c10[s][i].x, c11[s][i].x, W.h);
            o4.y = blend2h(c00[s][i].y, c01[s][i].y, c10[s][i].y, c11[s][i].y, W.h);
            o4.z = blend2h(c00[s][i].z, c01[s][i].z, c10[s][i].z, c11[s][i].z, W.h);
            o4.w = blend2h(c00[s][i].w, c01[s][i].w, c10[s][i].w, c11[s][i].w, W.h);
            *(uint4*)&samp[buf][p][j8 << 3] = o4;
        }
    };

    // LDS-only barrier: commit this wave's ds_writes (lgkmcnt), then barrier.
    auto ldsBarrier = [&]() {
        asm volatile("s_waitcnt lgkmcnt(0)\n\ts_barrier" ::: "memory");
    };

    // prologue: taps 0 and 1 into the pipe; params(2) staged
    readParams(0); issueInto(0);
    readParams(1); issueInto(1);
    afC[0] = *(const half8*)&wrow[0];
    afC[1] = *(const half8*)&wrow[32];
    blendStore(0, 0);                               // blend tap0 -> samp[0]
    readParams(2);

    #pragma unroll
    for (int k = 0; k < 9; ++k) {
        if (k <= 6) issueInto(k & 1);               // corners for tap k+2
        if (k < 8) {
            afN[0] = *(const half8*)&wrow[((k + 1) << 6)];
            afN[1] = *(const half8*)&wrow[((k + 1) << 6) + 32];
        }
        ldsBarrier();                               // samp[k&1] complete block-wide
        #pragma unroll
        for (int ch = 0; ch < 2; ++ch) {
            #pragma unroll
            for (int nt = 0; nt < 4; ++nt) {
                half8 bfrag = *(const half8*)&samp[k & 1][(nt << 4) + r][(ch << 5) + (q << 3)];
                acc[nt] = __builtin_amdgcn_mfma_f32_16x16x32_f16(afC[ch], bfrag, acc[nt], 0, 0, 0);
            }
        }
        if (k < 8) {
            blendStore((k + 1) & 1, (k + 1) & 1);   // corners issued at body k-1
            if (k <= 5) readParams(k + 3);          // params for issue at body k+1
            afC[0] = afN[0];
            afC[1] = afN[1];
        }
    }

    #pragma unroll
    for (int nt = 0; nt < 4; ++nt) {
        #pragma unroll
        for (int reg = 0; reg < 4; ++reg) {
            int oc  = (wv << 4) + (q << 2) + reg;
            int pos = pos0 + (nt << 4) + r;
            float v = acc[nt][reg] + bias[oc];
            out[(size_t)(((b << 6) + oc) << 14) + pos] = fmaxf(v, 0.f);
        }
    }
}

// ---------------------------------------------------------------------------
extern "C" void kernel_launch(void* const* d_in, const int* in_sizes, int n_in,
                              void* d_out, int out_size, void* d_ws, size_t ws_size,
                              hipStream_t stream) {
    const float* data  = (const float*)d_in[0];
    const float* w     = (const float*)d_in[1];
    const float* bias  = (const float*)d_in[2];
    const float* w_off = (const float*)d_in[3];
    const float* b_off = (const float*)d_in[4];
    const float* w_mod = (const float*)d_in[5];
    const float* b_mod = (const float*)d_in[6];
    float* out = (float*)d_out;

    char* ws = (char*)d_ws;
    unsigned short* dataT   = (unsigned short*)(ws + OFF_DATAT);
    float*          offP    = (float*)(ws + OFF_OFFP);
    unsigned short* wpackM  = (unsigned short*)(ws + OFF_WM);
    unsigned short* wq      = (unsigned short*)(ws + OFF_W27);
    float*          bias27  = (float*)(ws + OFF_B27);

    prep_k<<<2264, 256, 0, stream>>>(data, dataT, w, w_off, w_mod,
                                     b_off, b_mod, wpackM, wq, bias27);
    conv27_k<<<1024, 256, 0, stream>>>(dataT, wq, bias27, offP);
    deform_main_k<<<2048, 256, 0, stream>>>(dataT, wpackM, offP, bias, out);
}